// Round 5
// baseline (551.074 us; speedup 1.0000x reference)
//
#include <hip/hip_runtime.h>
#include <math.h>

// Problem constants
#define TOK   4096    // B*N
#define EDIM  512
#define HEADS 8
#define DHEAD 64
#define GCOLS 32768   // H*D*D

typedef unsigned short u16;
typedef _Float16 f16;
typedef __attribute__((ext_vector_type(8))) f16 f16x8;      // 8 fp16 = 4 VGPRs (MFMA A/B frag)
typedef __attribute__((ext_vector_type(4))) f16 f16x4;
typedef __attribute__((ext_vector_type(2))) f16 f16x2;
typedef __attribute__((ext_vector_type(4))) float f32x4;    // MFMA C/D frag
typedef __attribute__((ext_vector_type(4))) unsigned short u16x4;

typedef const __attribute__((address_space(1))) void* gas_ptr;
typedef __attribute__((address_space(3))) void* las_ptr;

__device__ __forceinline__ void gll16(const void* g, void* lds) {
  // async global->LDS, 16B/lane: per-lane global addr, wave-uniform LDS base,
  // lane i lands at lds + i*16
  __builtin_amdgcn_global_load_lds((gas_ptr)g, (las_ptr)lds, 16, 0, 0);
}

// Counted vmem wait: lets prefetch loads stay in flight across barriers.
#define WAITV(N) asm volatile("s_waitcnt vmcnt(" #N ")" ::: "memory")
// Raw barrier WITHOUT the implicit vmcnt(0) drain __syncthreads emits.
__device__ __forceinline__ void barrier_raw() { asm volatile("s_barrier" ::: "memory"); }

__device__ __forceinline__ u16 f2h_bits(float f) {
  union { f16 h; u16 u; } v; v.h = (f16)f;   // RNE
  return v.u;
}

// Abramowitz-Stegun 7.1.26 erf: |abs err| <= 1.5e-7, ~14 VALU insts.
__device__ __forceinline__ float fast_gelu(float x) {
  float s = x * 0.7071067811865475f;
  float ax = fabsf(s);
  float t = __builtin_amdgcn_rcpf(1.0f + 0.3275911f * ax);
  float poly = t * (0.254829592f + t * (-0.284496736f + t * (1.421413741f +
               t * (-1.453152027f + t * 1.061405429f))));
  float e = __expf(-ax * ax);
  float r = 1.0f - poly * e;
  float erfv = copysignf(r, s);
  return 0.5f * x * (1.0f + erfv);
}

// ---------------------------------------------------------------- cast x -> fp16
__global__ void cast_f16_k(const float* __restrict__ in, u16* __restrict__ out, int n) {
  int i = (blockIdx.x * blockDim.x + threadIdx.x) * 4;
  if (i + 3 < n) {
    float4 f = *(const float4*)(in + i);
    u16x4 h;
    h.x = f2h_bits(f.x); h.y = f2h_bits(f.y);
    h.z = f2h_bits(f.z); h.w = f2h_bits(f.w);
    *(u16x4*)(out + i) = h;
  }
}

// -------------------- transpose W[K][N] -> Wt[N][K] fp16
__global__ void transpose_f16_k(const float* __restrict__ in, u16* __restrict__ out,
                                int K, int N) {
  __shared__ float tile[32][33];
  int n0 = blockIdx.x * 32, k0 = blockIdx.y * 32;
  int tx = threadIdx.x, ty = threadIdx.y;  // (32,8)
  #pragma unroll
  for (int i = 0; i < 4; i++)
    tile[ty + i * 8][tx] = in[(size_t)(k0 + ty + i * 8) * N + n0 + tx];
  __syncthreads();
  #pragma unroll
  for (int i = 0; i < 4; i++)
    out[(size_t)(n0 + ty + i * 8) * K + k0 + tx] = f2h_bits(tile[tx][ty + i * 8]);
}

// ---------------------------------------------------------------- QKV GEMM
// 128x128 tile, BK=64, 4 waves (each 64x64), fp16 MFMA.
// v3: double-buffer + prefetch + COUNTED vmcnt(8) with raw s_barrier.
__global__ __launch_bounds__(256, 2) void qkv_gemm_k(
    const u16* __restrict__ xf, const u16* __restrict__ Wqt,
    const u16* __restrict__ Wkt, const u16* __restrict__ Wvt,
    const float* __restrict__ bq, const float* __restrict__ bk, const float* __restrict__ bv,
    u16* __restrict__ qho, u16* __restrict__ ko, u16* __restrict__ vTo) {
  __shared__ __align__(16) u16 As[2][16 * 512];   // 2 x 16KB
  __shared__ __align__(16) u16 Bs[2][16 * 512];   // 2 x 16KB  -> 64KB, 2 blk/CU
  const int which = blockIdx.z;
  const u16* Wt = which == 0 ? Wqt : (which == 1 ? Wkt : Wvt);
  const float* bias = which == 0 ? bq : (which == 1 ? bk : bv);
  const int m0 = blockIdx.x * 128;
  const int n0 = blockIdx.y * 128;
  const int tid = threadIdx.x;
  const int w = tid >> 6, lane = tid & 63, l15 = lane & 15, quad = lane >> 4;
  const int mhalf = w >> 1, nhalf = w & 1;

  f32x4 acc[4][4];
  #pragma unroll
  for (int i = 0; i < 4; i++)
    #pragma unroll
    for (int j = 0; j < 4; j++) acc[i][j] = f32x4{0.f, 0.f, 0.f, 0.f};

  auto stage = [&](int d, int kk) {
    #pragma unroll
    for (int i = 0; i < 8; i++) {
      int cb = w * 8 + i;
      if (cb < 16) {
        int ks = cb >> 3, mt = cb & 7;
        gll16(xf + (size_t)(m0 + mt * 16 + l15) * 512 + kk + ks * 32 + quad * 8,
              As[d] + cb * 512);
      } else {
        int bi = cb - 16, ks = bi >> 3, nt = bi & 7;
        gll16(Wt + (size_t)(n0 + nt * 16 + l15) * 512 + kk + ks * 32 + quad * 8,
              Bs[d] + bi * 512);
      }
    }
  };

  stage(0, 0);                     // 8 loads/wave in flight
  int cur = 0;
  for (int kt = 0; kt < 8; kt++) {
    if (kt < 7) { stage(cur ^ 1, (kt + 1) * 64); WAITV(8); }  // keep prefetch in flight
    else        { WAITV(0); }
    barrier_raw();                 // all waves' stage-kt data resident
    const u16* Asb = As[cur];
    const u16* Bsb = Bs[cur];
    #pragma unroll
    for (int ks = 0; ks < 2; ks++) {
      f16x8 a[4], b[4];
      #pragma unroll
      for (int mt = 0; mt < 4; mt++)
        a[mt] = *(const f16x8*)(Asb + (ks * 8 + mhalf * 4 + mt) * 512 + lane * 8);
      #pragma unroll
      for (int nt = 0; nt < 4; nt++)
        b[nt] = *(const f16x8*)(Bsb + (ks * 8 + nhalf * 4 + nt) * 512 + lane * 8);
      #pragma unroll
      for (int mt = 0; mt < 4; mt++)
        #pragma unroll
        for (int nt = 0; nt < 4; nt++)
          acc[mt][nt] = __builtin_amdgcn_mfma_f32_16x16x32_f16(a[mt], b[nt], acc[mt][nt], 0, 0, 0);
    }
    barrier_raw();                 // protect buf[cur] before next iter's stage()
    cur ^= 1;
  }
  #pragma unroll
  for (int nt = 0; nt < 4; nt++) {
    int col = n0 + (nhalf * 4 + nt) * 16 + l15;
    float bia = bias[col];
    int h = col >> 6, d = col & 63;
    #pragma unroll
    for (int mt = 0; mt < 4; mt++) {
      #pragma unroll
      for (int r = 0; r < 4; r++) {
        int t = m0 + (mhalf * 4 + mt) * 16 + quad * 4 + r;
        int b_ = t >> 10, n = t & 1023;
        float val = acc[mt][nt][r] + bia;
        size_t idx = (((size_t)(b_ * 8 + h) * 1024) + n) * 64 + d;
        if (which == 0)      qho[idx] = f2h_bits(val);
        else if (which == 1) ko[idx] = f2h_bits(val);
        else                 vTo[(((size_t)(b_ * 8 + h) * 64) + d) * 1024 + n] = f2h_bits(val);
      }
    }
  }
}

// ---------------------------------------------------------------- fused g-GEMM + q.g
// v5: v3 schedule (issue-before-wait, counted WAITV, two raw barriers) with a
// tile re-sized for 2 BLOCKS/CU: block = 64 tokens x head x 128 cols/stage,
// BK=64. LDS = As 2x8K + Bs 2x16K + Qs 8K + bgs 8K = 64KB -> 2 blocks/CU,
// grid 512. While one block's 8 waves sit at WAITV/s_barrier, the co-resident
// block computes (m114 overlap) -- the TLP that v2-v4 (1 blk/CU) lacked.
// 256 stages = 32 j-pairs x 8 kk; 3 loads/wave/stage (uniform -> per-wave
// vmcnt(3) literal is correct for every wave); 8 MFMA/wave/stage.
__global__ __launch_bounds__(512, 4) void qg_fused_k(
    const u16* __restrict__ xf, const u16* __restrict__ Wgt,
    const u16* __restrict__ bgh, const u16* __restrict__ qh,
    u16* __restrict__ qg16) {
  __shared__ __align__(16) u16 As[2][8 * 512];    // 2 x 8KB: 64 tok x 64 K
  __shared__ __align__(16) u16 Bs[2][16 * 512];   // 2 x 16KB: 128 cols x 64 K
  __shared__ __align__(16) u16 Qs[64 * 64];       // 8KB: q fp16 rows
  __shared__ __align__(16) f16 bgs[4096];         // 8KB: bg head slice (fp16)
  const int head = blockIdx.x & 7;                // XCD-pinned per head
  const int t0 = (blockIdx.x >> 3) * 64;          // 64 t-tiles x 8 heads = 512
  const int tid = threadIdx.x;
  const int w = tid >> 6, lane = tid & 63, l15 = lane & 15, quad = lane >> 4;
  const int wm = w >> 2;      // 0..1  (32-row half)
  const int ntA = w & 3;      // 0..3  (16-col e-tile)
  const int b_ = t0 >> 10, nseq0 = t0 & 1023;
  const u16* qbase = qh + (((size_t)(b_ * 8 + head) * 1024) + nseq0) * 64;

  // prologue staging: Qs (1 gll16/wave, contiguous 8KB) + bgs (1/wave, 8KB)
  gll16(qbase + (size_t)w * 512 + (size_t)lane * 8, Qs + (size_t)w * 512);
  gll16(bgh + (size_t)head * 4096 + w * 512 + lane * 8, bgs + w * 512);

  // Per stage: A 8 blocks (1/wave), B 16 blocks (2/wave). Block = 512 elems:
  // 16 rows/cols x 32 K, lane(l15,quad) -> row l15, K-chunk quad (store order
  // == fragment read order, both lane*16B).
  auto stage = [&](int d, int s) {
    int jp = s >> 3, kk = (s & 7) << 6;
    int c0 = head * 4096 + jp * 128;              // 128 cols = d-pair (2jp,2jp+1)
    {
      int ks = w >> 2, mg = w & 3;                // A block cb = w
      gll16(xf + (size_t)(t0 + mg * 16 + l15) * 512 + kk + ks * 32 + quad * 8,
            As[d] + w * 512);
    }
    #pragma unroll
    for (int i = 0; i < 2; i++) {
      int bi = w * 2 + i, ks = bi >> 3, nt = bi & 7;
      gll16(Wgt + (size_t)(c0 + nt * 16 + l15) * 512 + kk + ks * 32 + quad * 8,
            Bs[d] + bi * 512);
    }
  };

  f32x4 qg[2];
  #pragma unroll
  for (int i = 0; i < 2; i++) qg[i] = f32x4{0.f, 0.f, 0.f, 0.f};
  f32x4 zacc[2][2];                               // [mt][z]: z = which d of pair
  #pragma unroll
  for (int i = 0; i < 2; i++)
    #pragma unroll
    for (int z = 0; z < 2; z++) zacc[i][z] = f32x4{0.f, 0.f, 0.f, 0.f};

  stage(0, 0);                     // 3 loads/wave in flight (+2 prologue)
  int cur = 0;
  for (int s = 0; s < 256; s++) {
    if (s < 255) { stage(cur ^ 1, s + 1); WAITV(3); }  // stage-s done, prefetch flying
    else         { WAITV(0); }
    barrier_raw();                 // all waves' stage-s data resident
    const u16* Asb = As[cur];
    const u16* Bsb = Bs[cur];
    #pragma unroll
    for (int ks = 0; ks < 2; ks++) {
      f16x8 a[2];
      #pragma unroll
      for (int mt = 0; mt < 2; mt++)
        a[mt] = *(const f16x8*)(Asb + (ks * 4 + wm * 2 + mt) * 512 + lane * 8);
      #pragma unroll
      for (int z = 0; z < 2; z++) {
        int nt = z * 4 + ntA;
        f16x8 b = *(const f16x8*)(Bsb + (ks * 8 + nt) * 512 + lane * 8);
        #pragma unroll
        for (int mt = 0; mt < 2; mt++)
          zacc[mt][z] = __builtin_amdgcn_mfma_f32_16x16x32_f16(a[mt], b, zacc[mt][z], 0, 0, 0);
      }
    }
    if ((s & 7) == 7) {
      // epilogue for j-pair jp: bias (LDS fp16) + gelu + contract with fp16 q
      // over d = (2jp, 2jp+1). Overlaps the in-flight prefetch.
      int jp = s >> 3;
      float bgv[2];
      #pragma unroll
      for (int z = 0; z < 2; z++)
        bgv[z] = (float)bgs[jp * 128 + (z * 4 + ntA) * 16 + l15];
      const int d0 = 2 * jp;
      #pragma unroll
      for (int mt = 0; mt < 2; mt++) {
        #pragma unroll
        for (int r = 0; r < 4; r++) {
          int row = wm * 32 + mt * 16 + quad * 4 + r;
          f16x2 qp = *(const f16x2*)(Qs + row * 64 + d0);  // q[row][2jp..2jp+1]
          float g0 = fast_gelu(zacc[mt][0][r] + bgv[0]);
          float g1 = fast_gelu(zacc[mt][1][r] + bgv[1]);
          qg[mt][r] += (float)qp.x * g0 + (float)qp.y * g1;
        }
      }
      #pragma unroll
      for (int i = 0; i < 2; i++)
        #pragma unroll
        for (int z = 0; z < 2; z++) zacc[i][z] = f32x4{0.f, 0.f, 0.f, 0.f};
    }
    barrier_raw();                 // protect buf[cur] before next iter's stage()
    cur ^= 1;
  }
  // write complete qg as fp16 [B][H][N][D]
  const int eb = ntA * 16;
  #pragma unroll
  for (int mt = 0; mt < 2; mt++) {
    #pragma unroll
    for (int r = 0; r < 4; r++) {
      int t = t0 + wm * 32 + mt * 16 + quad * 4 + r;
      int bb = t >> 10, n = t & 1023;
      qg16[(((size_t)(bb * 8 + head) * 1024) + n) * 64 + eb + l15] = f2h_bits(qg[mt][r]);
    }
  }
}

// ---------------------------------------------------------------- flash attention
// Block = (b,h,qtile64), 4 waves x 16 q-rows. v3: counted vmcnt(4) + raw
// barriers; K/V prefetch stays in flight across the softmax.
__global__ __launch_bounds__(256, 2) void attn_k(
    const u16* __restrict__ qg16, const u16* __restrict__ kb,
    const u16* __restrict__ vTb, float* __restrict__ out) {
  __shared__ __align__(16) u16 Ks[2][8 * 512];
  __shared__ __align__(16) u16 Vs[2][8 * 512];
  __shared__ __align__(16) f16 Ps[4][16 * 72];    // per-wave P, row stride 72
  const int idx = blockIdx.x;
  const int bh = idx & 31;   // b*8+h -> XCD = bh%8
  const int qt = idx >> 5;
  const int b_ = bh >> 3, h = bh & 7;
  const int tid = threadIdx.x;
  const int w = tid >> 6, lane = tid & 63, l15 = lane & 15, quad = lane >> 4;

  const u16* qgB = qg16 + (size_t)bh * 1024 * 64;
  const u16* kB  = kb  + (size_t)bh * 1024 * 64;
  const u16* vB  = vTb + (size_t)bh * 64 * 1024;

  f16x8 aq[2];
  #pragma unroll
  for (int ks = 0; ks < 2; ks++)
    aq[ks] = *(const f16x8*)(qgB + (size_t)(qt * 64 + w * 16 + l15) * 64 + ks * 32 + quad * 8);

  f32x4 o[4];
  #pragma unroll
  for (int i = 0; i < 4; i++) o[i] = f32x4{0.f, 0.f, 0.f, 0.f};
  float m_old[4], l_old[4];
  #pragma unroll
  for (int r = 0; r < 4; r++) { m_old[r] = -1e30f; l_old[r] = 0.f; }

  auto stageKV = [&](int d, int kt) {
    #pragma unroll
    for (int i = 0; i < 2; i++) {
      int cb = w * 2 + i;
      int ks = cb >> 2, nt = cb & 3;
      gll16(kB + (size_t)(kt * 64 + nt * 16 + l15) * 64 + ks * 32 + quad * 8, Ks[d] + cb * 512);
      gll16(vB + (size_t)(nt * 16 + l15) * 1024 + kt * 64 + ks * 32 + quad * 8, Vs[d] + cb * 512);
    }
  };

  stageKV(0, 0);                   // 4 loads/wave in flight
  int cur = 0;
  for (int kt = 0; kt < 16; kt++) {
    if (kt < 15) { stageKV(cur ^ 1, kt + 1); WAITV(4); }
    else         { WAITV(0); }
    barrier_raw();
    f32x4 s[4];
    #pragma unroll
    for (int nt = 0; nt < 4; nt++) s[nt] = f32x4{0.f, 0.f, 0.f, 0.f};
    #pragma unroll
    for (int ks = 0; ks < 2; ks++)
      #pragma unroll
      for (int nt = 0; nt < 4; nt++) {
        f16x8 kf = *(const f16x8*)(Ks[cur] + (ks * 4 + nt) * 512 + lane * 8);
        s[nt] = __builtin_amdgcn_mfma_f32_16x16x32_f16(aq[ks], kf, s[nt], 0, 0, 0);
      }
    float rmax[4];
    #pragma unroll
    for (int r = 0; r < 4; r++)
      rmax[r] = fmaxf(fmaxf(s[0][r], s[1][r]), fmaxf(s[2][r], s[3][r]));
    #pragma unroll
    for (int off = 1; off < 16; off <<= 1)
      #pragma unroll
      for (int r = 0; r < 4; r++)
        rmax[r] = fmaxf(rmax[r], __shfl_xor(rmax[r], off));
    float alpha[4], rsum[4];
    #pragma unroll
    for (int r = 0; r < 4; r++) {
      float mn = fmaxf(m_old[r], rmax[r]);
      alpha[r] = __expf(m_old[r] - mn);
      m_old[r] = mn;
      rsum[r] = 0.f;
    }
    #pragma unroll
    for (int nt = 0; nt < 4; nt++)
      #pragma unroll
      for (int r = 0; r < 4; r++) {
        float p = __expf(s[nt][r] - m_old[r]);
        rsum[r] += p;
        Ps[w][(quad * 4 + r) * 72 + nt * 16 + l15] = (f16)p;
      }
    #pragma unroll
    for (int off = 1; off < 16; off <<= 1)
      #pragma unroll
      for (int r = 0; r < 4; r++)
        rsum[r] += __shfl_xor(rsum[r], off);
    #pragma unroll
    for (int r = 0; r < 4; r++) l_old[r] = l_old[r] * alpha[r] + rsum[r];
    #pragma unroll
    for (int nt = 0; nt < 4; nt++)
      #pragma unroll
      for (int r = 0; r < 4; r++) o[nt][r] *= alpha[r];
    #pragma unroll
    for (int ks = 0; ks < 2; ks++) {
      f16x8 pa = *(const f16x8*)(&Ps[w][l15 * 72 + ks * 32 + quad * 8]);
      #pragma unroll
      for (int nt = 0; nt < 4; nt++) {
        f16x8 vf = *(const f16x8*)(Vs[cur] + (ks * 4 + nt) * 512 + lane * 8);
        o[nt] = __builtin_amdgcn_mfma_f32_16x16x32_f16(pa, vf, o[nt], 0, 0, 0);
      }
    }
    barrier_raw();                 // protect Ks/Vs[cur] before next stageKV
    cur ^= 1;
  }
  #pragma unroll
  for (int r = 0; r < 4; r++) {
    float inv = 1.f / l_old[r];
    int n = qt * 64 + w * 16 + quad * 4 + r;
    #pragma unroll
    for (int nt = 0; nt < 4; nt++)
      out[((size_t)(b_ * 1024 + n)) * 512 + h * 64 + nt * 16 + l15] = o[nt][r] * inv;
  }
}

// ----------------------------------------------------------------------- host
extern "C" void kernel_launch(void* const* d_in, const int* in_sizes, int n_in,
                              void* d_out, int out_size, void* d_ws, size_t ws_size,
                              hipStream_t stream) {
  const float* x  = (const float*)d_in[0];
  const float* Wq = (const float*)d_in[1];
  const float* bq = (const float*)d_in[2];
  const float* Wk = (const float*)d_in[3];
  const float* bk = (const float*)d_in[4];
  const float* Wv = (const float*)d_in[5];
  const float* bv = (const float*)d_in[6];
  const float* Wg = (const float*)d_in[7];
  const float* bg = (const float*)d_in[8];
  float* out = (float*)d_out;

  const size_t NX = (size_t)TOK * EDIM;        // 2M elems
  const size_t NWG = (size_t)GCOLS * EDIM;     // 16.8M elems
  const size_t NW = (size_t)EDIM * EDIM;       // 256K elems

  char* p = (char*)d_ws;
  u16* xf  = (u16*)p; p += NX * 2;             // x fp16
  u16* Wgt = (u16*)p; p += NWG * 2;            // Wg^T fp16 (33.5 MB)
  u16* Wqt = (u16*)p; p += NW * 2;
  u16* Wkt = (u16*)p; p += NW * 2;
  u16* Wvt = (u16*)p; p += NW * 2;
  u16* qh  = (u16*)p; p += NX * 2;             // q fp16 [B][H][N][D]
  u16* kf  = (u16*)p; p += NX * 2;             // k fp16
  u16* vT  = (u16*)p; p += NX * 2;             // v^T fp16
  u16* qg16 = (u16*)p; p += NX * 2;            // qg fp16 [B][H][N][D] (complete)
  u16* bgh = (u16*)p; p += GCOLS * 2;          // bg fp16 (64KB)

  hipLaunchKernelGGL(cast_f16_k, dim3(NX / 1024), dim3(256), 0, stream,
                     x, xf, (int)NX);
  hipLaunchKernelGGL(cast_f16_k, dim3(GCOLS / 1024), dim3(256), 0, stream,
                     bg, bgh, GCOLS);
  hipLaunchKernelGGL(transpose_f16_k, dim3(EDIM / 32, EDIM / 32), dim3(32, 8), 0, stream,
                     Wq, Wqt, EDIM, EDIM);
  hipLaunchKernelGGL(transpose_f16_k, dim3(EDIM / 32, EDIM / 32), dim3(32, 8), 0, stream,
                     Wk, Wkt, EDIM, EDIM);
  hipLaunchKernelGGL(transpose_f16_k, dim3(EDIM / 32, EDIM / 32), dim3(32, 8), 0, stream,
                     Wv, Wvt, EDIM, EDIM);
  hipLaunchKernelGGL(transpose_f16_k, dim3(GCOLS / 32, EDIM / 32), dim3(32, 8), 0, stream,
                     Wg, Wgt, EDIM, GCOLS);
  hipLaunchKernelGGL(qkv_gemm_k, dim3(TOK / 128, EDIM / 128, 3), dim3(256), 0, stream,
                     xf, Wqt, Wkt, Wvt, bq, bk, bv, qh, kf, vT);
  hipLaunchKernelGGL(qg_fused_k, dim3(512), dim3(512), 0, stream,
                     xf, Wgt, bgh, qh, qg16);
  hipLaunchKernelGGL(attn_k, dim3(512), dim3(256), 0, stream,
                     qg16, kf, vT, out);
}

// Round 6
// 464.594 us; speedup vs baseline: 1.1861x; 1.1861x over previous
//
#include <hip/hip_runtime.h>
#include <math.h>

// Problem constants
#define TOK   4096    // B*N
#define EDIM  512
#define HEADS 8
#define DHEAD 64
#define GCOLS 32768   // H*D*D

typedef unsigned short u16;
typedef _Float16 f16;
typedef __attribute__((ext_vector_type(8))) f16 f16x8;      // 8 fp16 = 4 VGPRs (MFMA A/B frag)
typedef __attribute__((ext_vector_type(4))) f16 f16x4;
typedef __attribute__((ext_vector_type(4))) float f32x4;    // MFMA C/D frag
typedef __attribute__((ext_vector_type(4))) unsigned short u16x4;

typedef const __attribute__((address_space(1))) void* gas_ptr;
typedef __attribute__((address_space(3))) void* las_ptr;

__device__ __forceinline__ void gll16(const void* g, void* lds) {
  // async global->LDS, 16B/lane: per-lane global addr, wave-uniform LDS base,
  // lane i lands at lds + i*16
  __builtin_amdgcn_global_load_lds((gas_ptr)g, (las_ptr)lds, 16, 0, 0);
}

// Counted vmem wait: lets prefetch loads stay in flight across barriers.
#define WAITV(N) asm volatile("s_waitcnt vmcnt(" #N ")" ::: "memory")
// Raw barrier WITHOUT the implicit vmcnt(0) drain __syncthreads emits.
__device__ __forceinline__ void barrier_raw() { asm volatile("s_barrier" ::: "memory"); }

__device__ __forceinline__ u16 f2h_bits(float f) {
  union { f16 h; u16 u; } v; v.h = (f16)f;   // RNE
  return v.u;
}

// Abramowitz-Stegun 7.1.26 erf: |abs err| <= 1.5e-7, ~14 VALU insts.
__device__ __forceinline__ float fast_gelu(float x) {
  float s = x * 0.7071067811865475f;
  float ax = fabsf(s);
  float t = __builtin_amdgcn_rcpf(1.0f + 0.3275911f * ax);
  float poly = t * (0.254829592f + t * (-0.284496736f + t * (1.421413741f +
               t * (-1.453152027f + t * 1.061405429f))));
  float e = __expf(-ax * ax);
  float r = 1.0f - poly * e;
  float erfv = copysignf(r, s);
  return 0.5f * x * (1.0f + erfv);
}

// ---------------------------------------------------------------- cast x -> fp16
__global__ void cast_f16_k(const float* __restrict__ in, u16* __restrict__ out, int n) {
  int i = (blockIdx.x * blockDim.x + threadIdx.x) * 4;
  if (i + 3 < n) {
    float4 f = *(const float4*)(in + i);
    u16x4 h;
    h.x = f2h_bits(f.x); h.y = f2h_bits(f.y);
    h.z = f2h_bits(f.z); h.w = f2h_bits(f.w);
    *(u16x4*)(out + i) = h;
  }
}

// -------------------- transpose W[K][N] -> Wt[N][K] fp16
__global__ void transpose_f16_k(const float* __restrict__ in, u16* __restrict__ out,
                                int K, int N) {
  __shared__ float tile[32][33];
  int n0 = blockIdx.x * 32, k0 = blockIdx.y * 32;
  int tx = threadIdx.x, ty = threadIdx.y;  // (32,8)
  #pragma unroll
  for (int i = 0; i < 4; i++)
    tile[ty + i * 8][tx] = in[(size_t)(k0 + ty + i * 8) * N + n0 + tx];
  __syncthreads();
  #pragma unroll
  for (int i = 0; i < 4; i++)
    out[(size_t)(n0 + ty + i * 8) * K + k0 + tx] = f2h_bits(tile[tx][ty + i * 8]);
}

// ---------------------------------------------------------------- QKV GEMM
// 128x128 tile, BK=64, 4 waves (each 64x64), fp16 MFMA.
// v3: double-buffer + prefetch + COUNTED vmcnt(8) with raw s_barrier.
__global__ __launch_bounds__(256, 2) void qkv_gemm_k(
    const u16* __restrict__ xf, const u16* __restrict__ Wqt,
    const u16* __restrict__ Wkt, const u16* __restrict__ Wvt,
    const float* __restrict__ bq, const float* __restrict__ bk, const float* __restrict__ bv,
    u16* __restrict__ qho, u16* __restrict__ ko, u16* __restrict__ vTo) {
  __shared__ __align__(16) u16 As[2][16 * 512];   // 2 x 16KB
  __shared__ __align__(16) u16 Bs[2][16 * 512];   // 2 x 16KB  -> 64KB, 2 blk/CU
  const int which = blockIdx.z;
  const u16* Wt = which == 0 ? Wqt : (which == 1 ? Wkt : Wvt);
  const float* bias = which == 0 ? bq : (which == 1 ? bk : bv);
  const int m0 = blockIdx.x * 128;
  const int n0 = blockIdx.y * 128;
  const int tid = threadIdx.x;
  const int w = tid >> 6, lane = tid & 63, l15 = lane & 15, quad = lane >> 4;
  const int mhalf = w >> 1, nhalf = w & 1;

  f32x4 acc[4][4];
  #pragma unroll
  for (int i = 0; i < 4; i++)
    #pragma unroll
    for (int j = 0; j < 4; j++) acc[i][j] = f32x4{0.f, 0.f, 0.f, 0.f};

  auto stage = [&](int d, int kk) {
    #pragma unroll
    for (int i = 0; i < 8; i++) {
      int cb = w * 8 + i;
      if (cb < 16) {
        int ks = cb >> 3, mt = cb & 7;
        gll16(xf + (size_t)(m0 + mt * 16 + l15) * 512 + kk + ks * 32 + quad * 8,
              As[d] + cb * 512);
      } else {
        int bi = cb - 16, ks = bi >> 3, nt = bi & 7;
        gll16(Wt + (size_t)(n0 + nt * 16 + l15) * 512 + kk + ks * 32 + quad * 8,
              Bs[d] + bi * 512);
      }
    }
  };

  stage(0, 0);                     // 8 loads/wave in flight
  int cur = 0;
  for (int kt = 0; kt < 8; kt++) {
    if (kt < 7) { stage(cur ^ 1, (kt + 1) * 64); WAITV(8); }  // keep prefetch in flight
    else        { WAITV(0); }
    barrier_raw();                 // all waves' stage-kt data resident
    const u16* Asb = As[cur];
    const u16* Bsb = Bs[cur];
    #pragma unroll
    for (int ks = 0; ks < 2; ks++) {
      f16x8 a[4], b[4];
      #pragma unroll
      for (int mt = 0; mt < 4; mt++)
        a[mt] = *(const f16x8*)(Asb + (ks * 8 + mhalf * 4 + mt) * 512 + lane * 8);
      #pragma unroll
      for (int nt = 0; nt < 4; nt++)
        b[nt] = *(const f16x8*)(Bsb + (ks * 8 + nhalf * 4 + nt) * 512 + lane * 8);
      #pragma unroll
      for (int mt = 0; mt < 4; mt++)
        #pragma unroll
        for (int nt = 0; nt < 4; nt++)
          acc[mt][nt] = __builtin_amdgcn_mfma_f32_16x16x32_f16(a[mt], b[nt], acc[mt][nt], 0, 0, 0);
    }
    barrier_raw();                 // protect buf[cur] before next iter's stage()
    cur ^= 1;
  }
  #pragma unroll
  for (int nt = 0; nt < 4; nt++) {
    int col = n0 + (nhalf * 4 + nt) * 16 + l15;
    float bia = bias[col];
    int h = col >> 6, d = col & 63;
    #pragma unroll
    for (int mt = 0; mt < 4; mt++) {
      #pragma unroll
      for (int r = 0; r < 4; r++) {
        int t = m0 + (mhalf * 4 + mt) * 16 + quad * 4 + r;
        int b_ = t >> 10, n = t & 1023;
        float val = acc[mt][nt][r] + bia;
        size_t idx = (((size_t)(b_ * 8 + h) * 1024) + n) * 64 + d;
        if (which == 0)      qho[idx] = f2h_bits(val);
        else if (which == 1) ko[idx] = f2h_bits(val);
        else                 vTo[(((size_t)(b_ * 8 + h) * 64) + d) * 1024 + n] = f2h_bits(val);
      }
    }
  }
}

// ---------------------------------------------------------------- fused g-GEMM + q.g
// v6: qkv_gemm geometry (128 tok x 128 cols, 256 thr, 4 waves, 32 MFMA/wave/
// stage) + P=4 d-split partials. Block = (t-tile, head, d-quarter): 8 j-pairs
// x 8 kk = 64 stages, v3 counted-vmcnt schedule. Grid 1024 = t*32+(head*4+dq)
// -> XCD = (4*head+dq)%8: each XCD streams only its 4 x 1MB Wgt panels = 4MB
// = its L2 -> B-loads become L2 hits. LDS 70KB -> 2 independent blocks/CU
// (two barrier domains at full per-stage density -- v5's mistake avoided).
// Epilogue per jp: gelu + contract with q over d=(2jp,2jp+1); cross-nhalf
// LDS reduction at end; fp32 partial out, summed by attn (R0-proven).
__global__ __launch_bounds__(256, 2) void qg_fused_k(
    const u16* __restrict__ xf, const u16* __restrict__ Wgt,
    const u16* __restrict__ bgh, const u16* __restrict__ qh,
    float* __restrict__ qgp) {
  __shared__ __align__(16) u16 As[2][16 * 512];   // 2 x 16KB: 128 tok x 64 K
  __shared__ __align__(16) u16 Bs[2][16 * 512];   // 2 x 16KB: 128 cols x 64 K
  __shared__ __align__(16) f16 Qs[128 * 16];      // 4KB: q rows, this d-quarter
  __shared__ __align__(16) f16 bgs[16 * 64];      // 2KB: bias, this (head,dq)
  const int bid = blockIdx.x;
  const int dq = bid & 3, head = (bid >> 2) & 7;
  const int t0 = (bid >> 5) * 128;
  const int tid = threadIdx.x;
  const int w = tid >> 6, lane = tid & 63, l15 = lane & 15, quad = lane >> 4;
  const int mhalf = w >> 1, nhalf = w & 1;
  const int b_ = t0 >> 10, nseq0 = t0 & 1023;
  const int bh = b_ * 8 + head;
  const u16* qbase = qh + (((size_t)bh * 1024) + nseq0) * 64;

  // prologue: 6 jobs (0-3 Qs quarters, 4-5 bgs halves) padded to 8 for
  // UNIFORM 2 loads/wave (jobs 6,7 duplicate 0,1 -- same data, same dest).
  #pragma unroll
  for (int i = 0; i < 2; i++) {
    int job = w * 2 + i; if (job >= 6) job -= 6;
    if (job < 4) {
      // Qs rows job*32..+32, 16 d-cols: lane -> row (lane>>1), half (lane&1)
      gll16(qbase + (size_t)(job * 32 + (lane >> 1)) * 64 + dq * 16 + (lane & 1) * 8,
            (f16*)Qs + job * 512);
    } else {
      int j = job - 4;
      gll16(bgh + (size_t)head * 4096 + (dq * 16 + j * 8 + (lane >> 3)) * 64 + (lane & 7) * 8,
            (f16*)bgs + j * 512);
    }
  }

  // Per stage: A 16 blocks (4/wave) + B 16 blocks (4/wave) = 8 gll16/wave.
  auto stage = [&](int d, int s) {
    int jp = s >> 3, kk = (s & 7) << 6;
    const u16* bsrc = Wgt + (size_t)(head * 4096 + (dq * 16 + jp * 2) * 64) * 512;
    #pragma unroll
    for (int i = 0; i < 4; i++) {
      int cb = w * 4 + i, ks = cb >> 3, mt = cb & 7;
      gll16(xf + (size_t)(t0 + mt * 16 + l15) * 512 + kk + ks * 32 + quad * 8,
            As[d] + cb * 512);
    }
    #pragma unroll
    for (int i = 0; i < 4; i++) {
      int bi = w * 4 + i, ks = bi >> 3, nt = bi & 7;
      gll16(bsrc + (size_t)(nt * 16 + l15) * 512 + kk + ks * 32 + quad * 8,
            Bs[d] + bi * 512);
    }
  };

  f32x4 acc[4][4], qgacc[4][4];
  #pragma unroll
  for (int i = 0; i < 4; i++)
    #pragma unroll
    for (int j = 0; j < 4; j++) {
      acc[i][j] = f32x4{0.f, 0.f, 0.f, 0.f};
      qgacc[i][j] = f32x4{0.f, 0.f, 0.f, 0.f};
    }

  stage(0, 0);                     // 8 loads/wave in flight (+2 prologue)
  for (int s = 0; s < 64; s++) {
    if (s < 63) { stage((s + 1) & 1, s + 1); WAITV(8); }  // stage-s done
    else        { WAITV(0); }
    barrier_raw();                 // all waves' stage-s data resident
    const u16* Asb = As[s & 1];
    const u16* Bsb = Bs[s & 1];
    #pragma unroll
    for (int ks = 0; ks < 2; ks++) {
      f16x8 a[4], b[4];
      #pragma unroll
      for (int mt = 0; mt < 4; mt++)
        a[mt] = *(const f16x8*)(Asb + (ks * 8 + mhalf * 4 + mt) * 512 + lane * 8);
      #pragma unroll
      for (int nt = 0; nt < 4; nt++)
        b[nt] = *(const f16x8*)(Bsb + (ks * 8 + nhalf * 4 + nt) * 512 + lane * 8);
      #pragma unroll
      for (int mt = 0; mt < 4; mt++)
        #pragma unroll
        for (int nt = 0; nt < 4; nt++)
          acc[mt][nt] = __builtin_amdgcn_mfma_f32_16x16x32_f16(a[mt], b[nt], acc[mt][nt], 0, 0, 0);
    }
    if ((s & 7) == 7) {
      // epilogue for j-pair jp: this wave's d = dq*16 + jp*2 + nhalf.
      // bias + gelu + contract with q[tok][d]; overlaps in-flight prefetch.
      int jp = s >> 3;
      int dloc = jp * 2 + nhalf;
      float bgv[4];
      #pragma unroll
      for (int nt = 0; nt < 4; nt++)
        bgv[nt] = (float)bgs[dloc * 64 + nt * 16 + l15];
      #pragma unroll
      for (int mt = 0; mt < 4; mt++) {
        #pragma unroll
        for (int r = 0; r < 4; r++) {
          int row = mhalf * 64 + mt * 16 + quad * 4 + r;
          float qv = (float)Qs[row * 16 + dloc];   // broadcast within quad
          #pragma unroll
          for (int nt = 0; nt < 4; nt++)
            qgacc[mt][nt][r] += qv * fast_gelu(acc[mt][nt][r] + bgv[nt]);
        }
      }
      #pragma unroll
      for (int i = 0; i < 4; i++)
        #pragma unroll
        for (int j = 0; j < 4; j++) acc[i][j] = f32x4{0.f, 0.f, 0.f, 0.f};
    }
    barrier_raw();                 // protect buf before next iter's stage()
  }
  // cross-nhalf reduction (both nhalf waves hold full [tok][e] partial grids)
  float* red = (float*)As;         // 32KB = 128 x 64 floats, loads all drained
  if (nhalf == 1) {
    #pragma unroll
    for (int mt = 0; mt < 4; mt++)
      #pragma unroll
      for (int r = 0; r < 4; r++) {
        int tok = mhalf * 64 + mt * 16 + quad * 4 + r;
        #pragma unroll
        for (int nt = 0; nt < 4; nt++)
          red[tok * 64 + nt * 16 + l15] = qgacc[mt][nt][r];
      }
  }
  barrier_raw();
  if (nhalf == 0) {
    float* outp = qgp + ((size_t)dq * 32 + bh) * 1024 * 64;
    #pragma unroll
    for (int mt = 0; mt < 4; mt++)
      #pragma unroll
      for (int r = 0; r < 4; r++) {
        int tok = mhalf * 64 + mt * 16 + quad * 4 + r;
        int n = nseq0 + tok;
        #pragma unroll
        for (int nt = 0; nt < 4; nt++)
          outp[(size_t)n * 64 + nt * 16 + l15] =
              qgacc[mt][nt][r] + red[tok * 64 + nt * 16 + l15];
      }
  }
}

// ---------------------------------------------------------------- flash attention
// Block = (b,h,qtile64), 4 waves x 16 q-rows. v6: qg = sum of 4 fp32 d-split
// partials (one-time per block); counted vmcnt(4) + raw barriers.
__global__ __launch_bounds__(256, 2) void attn_k(
    const float* __restrict__ qgp, const u16* __restrict__ kb,
    const u16* __restrict__ vTb, float* __restrict__ out) {
  __shared__ __align__(16) u16 Ks[2][8 * 512];
  __shared__ __align__(16) u16 Vs[2][8 * 512];
  __shared__ __align__(16) f16 Ps[4][16 * 72];    // per-wave P, row stride 72
  const int idx = blockIdx.x;
  const int bh = idx & 31;   // b*8+h -> XCD = bh%8
  const int qt = idx >> 5;
  const int b_ = bh >> 3, h = bh & 7;
  const int tid = threadIdx.x;
  const int w = tid >> 6, lane = tid & 63, l15 = lane & 15, quad = lane >> 4;

  const float* qgB = qgp + (size_t)bh * 1024 * 64;
  const size_t PS = (size_t)32 * 1024 * 64;       // partial stride (2M floats)
  const u16* kB  = kb  + (size_t)bh * 1024 * 64;
  const u16* vB  = vTb + (size_t)bh * 64 * 1024;

  f16x8 aq[2];
  #pragma unroll
  for (int ks = 0; ks < 2; ks++) {
    size_t off = (size_t)(qt * 64 + w * 16 + l15) * 64 + ks * 32 + quad * 8;
    f16x8 v;
    #pragma unroll
    for (int e = 0; e < 8; e++)
      v[e] = (f16)(qgB[off + e] + qgB[PS + off + e] +
                   qgB[2 * PS + off + e] + qgB[3 * PS + off + e]);
    aq[ks] = v;
  }

  f32x4 o[4];
  #pragma unroll
  for (int i = 0; i < 4; i++) o[i] = f32x4{0.f, 0.f, 0.f, 0.f};
  float m_old[4], l_old[4];
  #pragma unroll
  for (int r = 0; r < 4; r++) { m_old[r] = -1e30f; l_old[r] = 0.f; }

  auto stageKV = [&](int d, int kt) {
    #pragma unroll
    for (int i = 0; i < 2; i++) {
      int cb = w * 2 + i;
      int ks = cb >> 2, nt = cb & 3;
      gll16(kB + (size_t)(kt * 64 + nt * 16 + l15) * 64 + ks * 32 + quad * 8, Ks[d] + cb * 512);
      gll16(vB + (size_t)(nt * 16 + l15) * 1024 + kt * 64 + ks * 32 + quad * 8, Vs[d] + cb * 512);
    }
  };

  stageKV(0, 0);                   // 4 loads/wave in flight
  int cur = 0;
  for (int kt = 0; kt < 16; kt++) {
    if (kt < 15) { stageKV(cur ^ 1, kt + 1); WAITV(4); }
    else         { WAITV(0); }
    barrier_raw();
    f32x4 s[4];
    #pragma unroll
    for (int nt = 0; nt < 4; nt++) s[nt] = f32x4{0.f, 0.f, 0.f, 0.f};
    #pragma unroll
    for (int ks = 0; ks < 2; ks++)
      #pragma unroll
      for (int nt = 0; nt < 4; nt++) {
        f16x8 kf = *(const f16x8*)(Ks[cur] + (ks * 4 + nt) * 512 + lane * 8);
        s[nt] = __builtin_amdgcn_mfma_f32_16x16x32_f16(aq[ks], kf, s[nt], 0, 0, 0);
      }
    float rmax[4];
    #pragma unroll
    for (int r = 0; r < 4; r++)
      rmax[r] = fmaxf(fmaxf(s[0][r], s[1][r]), fmaxf(s[2][r], s[3][r]));
    #pragma unroll
    for (int off = 1; off < 16; off <<= 1)
      #pragma unroll
      for (int r = 0; r < 4; r++)
        rmax[r] = fmaxf(rmax[r], __shfl_xor(rmax[r], off));
    float alpha[4], rsum[4];
    #pragma unroll
    for (int r = 0; r < 4; r++) {
      float mn = fmaxf(m_old[r], rmax[r]);
      alpha[r] = __expf(m_old[r] - mn);
      m_old[r] = mn;
      rsum[r] = 0.f;
    }
    #pragma unroll
    for (int nt = 0; nt < 4; nt++)
      #pragma unroll
      for (int r = 0; r < 4; r++) {
        float p = __expf(s[nt][r] - m_old[r]);
        rsum[r] += p;
        Ps[w][(quad * 4 + r) * 72 + nt * 16 + l15] = (f16)p;
      }
    #pragma unroll
    for (int off = 1; off < 16; off <<= 1)
      #pragma unroll
      for (int r = 0; r < 4; r++)
        rsum[r] += __shfl_xor(rsum[r], off);
    #pragma unroll
    for (int r = 0; r < 4; r++) l_old[r] = l_old[r] * alpha[r] + rsum[r];
    #pragma unroll
    for (int nt = 0; nt < 4; nt++)
      #pragma unroll
      for (int r = 0; r < 4; r++) o[nt][r] *= alpha[r];
    #pragma unroll
    for (int ks = 0; ks < 2; ks++) {
      f16x8 pa = *(const f16x8*)(&Ps[w][l15 * 72 + ks * 32 + quad * 8]);
      #pragma unroll
      for (int nt = 0; nt < 4; nt++) {
        f16x8 vf = *(const f16x8*)(Vs[cur] + (ks * 4 + nt) * 512 + lane * 8);
        o[nt] = __builtin_amdgcn_mfma_f32_16x16x32_f16(pa, vf, o[nt], 0, 0, 0);
      }
    }
    barrier_raw();                 // protect Ks/Vs[cur] before next stageKV
    cur ^= 1;
  }
  #pragma unroll
  for (int r = 0; r < 4; r++) {
    float inv = 1.f / l_old[r];
    int n = qt * 64 + w * 16 + quad * 4 + r;
    #pragma unroll
    for (int nt = 0; nt < 4; nt++)
      out[((size_t)(b_ * 1024 + n)) * 512 + h * 64 + nt * 16 + l15] = o[nt][r] * inv;
  }
}

// ----------------------------------------------------------------------- host
extern "C" void kernel_launch(void* const* d_in, const int* in_sizes, int n_in,
                              void* d_out, int out_size, void* d_ws, size_t ws_size,
                              hipStream_t stream) {
  const float* x  = (const float*)d_in[0];
  const float* Wq = (const float*)d_in[1];
  const float* bq = (const float*)d_in[2];
  const float* Wk = (const float*)d_in[3];
  const float* bk = (const float*)d_in[4];
  const float* Wv = (const float*)d_in[5];
  const float* bv = (const float*)d_in[6];
  const float* Wg = (const float*)d_in[7];
  const float* bg = (const float*)d_in[8];
  float* out = (float*)d_out;

  const size_t NX = (size_t)TOK * EDIM;        // 2M elems
  const size_t NWG = (size_t)GCOLS * EDIM;     // 16.8M elems
  const size_t NW = (size_t)EDIM * EDIM;       // 256K elems

  char* p = (char*)d_ws;
  u16* xf  = (u16*)p; p += NX * 2;             // x fp16
  u16* Wgt = (u16*)p; p += NWG * 2;            // Wg^T fp16 (33.5 MB)
  u16* Wqt = (u16*)p; p += NW * 2;
  u16* Wkt = (u16*)p; p += NW * 2;
  u16* Wvt = (u16*)p; p += NW * 2;
  u16* qh  = (u16*)p; p += NX * 2;             // q fp16 [B][H][N][D]
  u16* kf  = (u16*)p; p += NX * 2;             // k fp16
  u16* vT  = (u16*)p; p += NX * 2;             // v^T fp16
  float* qgp = (float*)p; p += NX * 4 * 4;     // qg fp32 partials [4][B*H][N][D] (32MB)
  u16* bgh = (u16*)p; p += GCOLS * 2;          // bg fp16 (64KB)

  hipLaunchKernelGGL(cast_f16_k, dim3(NX / 1024), dim3(256), 0, stream,
                     x, xf, (int)NX);
  hipLaunchKernelGGL(cast_f16_k, dim3(GCOLS / 1024), dim3(256), 0, stream,
                     bg, bgh, GCOLS);
  hipLaunchKernelGGL(transpose_f16_k, dim3(EDIM / 32, EDIM / 32), dim3(32, 8), 0, stream,
                     Wq, Wqt, EDIM, EDIM);
  hipLaunchKernelGGL(transpose_f16_k, dim3(EDIM / 32, EDIM / 32), dim3(32, 8), 0, stream,
                     Wk, Wkt, EDIM, EDIM);
  hipLaunchKernelGGL(transpose_f16_k, dim3(EDIM / 32, EDIM / 32), dim3(32, 8), 0, stream,
                     Wv, Wvt, EDIM, EDIM);
  hipLaunchKernelGGL(transpose_f16_k, dim3(GCOLS / 32, EDIM / 32), dim3(32, 8), 0, stream,
                     Wg, Wgt, EDIM, GCOLS);
  hipLaunchKernelGGL(qkv_gemm_k, dim3(TOK / 128, EDIM / 128, 3), dim3(256), 0, stream,
                     xf, Wqt, Wkt, Wvt, bq, bk, bv, qh, kf, vT);
  hipLaunchKernelGGL(qg_fused_k, dim3(1024), dim3(256), 0, stream,
                     xf, Wgt, bgh, qh, qgp);
  hipLaunchKernelGGL(attn_k, dim3(512), dim3(256), 0, stream,
                     qgp, kf, vT, out);
}